// Round 2
// baseline (5439.964 us; speedup 1.0000x reference)
//
#include <hip/hip_runtime.h>
#include <stdint.h>

#define NROWS  8192
#define DMODEL 768
#define DSAE   24576
#define TOPK   64

// =================== Kernel 1: pre = x @ W_enc + b_enc (fp32) ===================
// 128x128 tile, BK=16, 256 threads, 8x8 register microtile per thread.
#define BM 128
#define BN 128
#define BK 16
#define APAD 132   // pad so transposed A-writes are only 2-way bank conflicted (free)

__global__ __launch_bounds__(256)
void gemm_enc(const float* __restrict__ x, const float* __restrict__ W,
              const float* __restrict__ bias, float* __restrict__ pre)
{
    __shared__ float As[BK][APAD];   // As[k][m] = x[bm+m][kt+k]
    __shared__ float Bs[BK][BN];     // Bs[k][n] = W[kt+k][bn+n]

    const int tid = threadIdx.x;
    const int bm = blockIdx.y * BM;
    const int bn = blockIdx.x * BN;
    const int ty = tid >> 4;         // 0..15
    const int tx = tid & 15;         // 0..15

    float acc[8][8];
    #pragma unroll
    for (int i = 0; i < 8; ++i)
        #pragma unroll
        for (int j = 0; j < 8; ++j) acc[i][j] = 0.f;

    const int am  = tid >> 2;          // A: row in tile (l=0), +64 for l=1
    const int akq = (tid & 3) * 4;     // A: k offset (float4 along k)
    const int bk  = tid >> 5;          // B: k row (l=0), +8 for l=1
    const int bnq = (tid & 31) * 4;    // B: n offset (float4 along n)

    for (int kt = 0; kt < DMODEL; kt += BK) {
        #pragma unroll
        for (int l = 0; l < 2; ++l) {
            const int m = am + l * 64;
            float4 av = *(const float4*)(x + (size_t)(bm + m) * DMODEL + kt + akq);
            As[akq + 0][m] = av.x;
            As[akq + 1][m] = av.y;
            As[akq + 2][m] = av.z;
            As[akq + 3][m] = av.w;
            const int k = bk + l * 8;
            *(float4*)(&Bs[k][bnq]) = *(const float4*)(W + (size_t)(kt + k) * DSAE + bn + bnq);
        }
        __syncthreads();
        #pragma unroll
        for (int k = 0; k < BK; ++k) {
            float4 a0 = *(const float4*)(&As[k][ty * 8]);
            float4 a1 = *(const float4*)(&As[k][ty * 8 + 4]);
            float4 b0 = *(const float4*)(&Bs[k][tx * 8]);
            float4 b1 = *(const float4*)(&Bs[k][tx * 8 + 4]);
            const float a[8] = {a0.x, a0.y, a0.z, a0.w, a1.x, a1.y, a1.z, a1.w};
            const float b[8] = {b0.x, b0.y, b0.z, b0.w, b1.x, b1.y, b1.z, b1.w};
            #pragma unroll
            for (int i = 0; i < 8; ++i)
                #pragma unroll
                for (int j = 0; j < 8; ++j)
                    acc[i][j] += a[i] * b[j];
        }
        __syncthreads();
    }

    float4 be0 = *(const float4*)(bias + bn + tx * 8);
    float4 be1 = *(const float4*)(bias + bn + tx * 8 + 4);
    const float be[8] = {be0.x, be0.y, be0.z, be0.w, be1.x, be1.y, be1.z, be1.w};
    #pragma unroll
    for (int i = 0; i < 8; ++i) {
        float* dst = pre + (size_t)(bm + ty * 8 + i) * DSAE + bn + tx * 8;
        *(float4*)(dst)     = make_float4(acc[i][0] + be[0], acc[i][1] + be[1],
                                          acc[i][2] + be[2], acc[i][3] + be[3]);
        *(float4*)(dst + 4) = make_float4(acc[i][4] + be[4], acc[i][5] + be[5],
                                          acc[i][6] + be[6], acc[i][7] + be[7]);
    }
}

// =================== Kernel 2: per-row top-64 select + sparsify + decode ===================
#define NT2 512

__device__ __forceinline__ unsigned sortable(float f) {
    // monotonic float->uint map: larger float => larger uint
    unsigned u = __float_as_uint(f);
    return u ^ ((u & 0x80000000u) ? 0xFFFFFFFFu : 0x80000000u);
}

__global__ __launch_bounds__(NT2)
void topk_decode(float* __restrict__ lat, const float* __restrict__ Wd,
                 float* __restrict__ out)
{
    const int row = blockIdx.x;
    const int tid = threadIdx.x;
    float* rowp = lat + (size_t)row * DSAE;

    __shared__ int hist[256];
    __shared__ int s_bucket, s_krem, s_total_eq;
    __shared__ float sel_v[TOPK];
    __shared__ int   sel_j[TOPK];
    __shared__ int   sel_cnt;
    __shared__ int   s_cutoff;

    // Floor filter: pre_act ~ N(0, ~1.4); E[#elems >= 2.0] ~ 1900 >> 64.
    // sortable(2.0f) = 0xC0000000. Unconditional fallback below if it ever fails.
    unsigned u_floor = 0xC0000000u;
    unsigned pbase = 0;
    int k_rem = TOPK;

    #pragma unroll 1
    for (int pass = 0; pass < 4; ++pass) {
        const int shift = 24 - 8 * pass;
        const unsigned mask = pass ? (0xFFFFFFFFu << (32 - 8 * pass)) : 0u;
        for (;;) {
            if (tid < 256) hist[tid] = 0;
            __syncthreads();
            for (int i = tid; i < DSAE; i += NT2) {
                unsigned u = sortable(rowp[i]);
                if (u >= u_floor && (u & mask) == pbase)
                    atomicAdd(&hist[(u >> shift) & 255], 1);
            }
            __syncthreads();
            if (tid == 0) {
                int acc = 0;
                int b = 255;
                for (; b >= 0; --b) {
                    int h = hist[b];
                    if (acc + h >= k_rem) break;
                    acc += h;
                }
                s_bucket   = b;
                s_krem     = (b >= 0) ? (k_rem - acc) : -1;
                s_total_eq = (b >= 0) ? hist[b] : 0;
            }
            __syncthreads();
            if (s_bucket >= 0) break;
            u_floor = 0;          // fallback: redo this pass over all elements
            __syncthreads();
        }
        pbase |= ((unsigned)s_bucket) << shift;
        k_rem = s_krem;
        __syncthreads();
    }

    const unsigned T = pbase;        // sortable-uint of the 64th largest value
    const int need_eq = k_rem;       // how many ==T elements are inside top-64 (>=1)
    const int total_eq = s_total_eq; // how many ==T elements exist

    if (tid == 0) { sel_cnt = 0; s_cutoff = DSAE; }
    if (tid < TOPK) { sel_v[tid] = 0.f; sel_j[tid] = 0; }
    __syncthreads();

    if (total_eq != need_eq) {
        // rare exact-tie path: jax.lax.top_k keeps lowest indices among ties
        if (tid == 0) {
            int c = 0, cut = DSAE;
            for (int i = 0; i < DSAE; ++i) {
                if (sortable(rowp[i]) == T) {
                    if (++c == need_eq) { cut = i; break; }
                }
            }
            s_cutoff = cut;
        }
        __syncthreads();
    }
    const int cutoff = s_cutoff;

    // sparsify in place + collect the 64 selected (j, v)
    for (int i4 = tid; i4 < DSAE / 4; i4 += NT2) {
        float4 v = *(const float4*)(rowp + i4 * 4);
        float vv[4] = {v.x, v.y, v.z, v.w};
        float ov[4];
        #pragma unroll
        for (int c = 0; c < 4; ++c) {
            const int i = i4 * 4 + c;
            const unsigned u = sortable(vv[c]);
            const bool keep = (u > T) || (u == T && i <= cutoff);
            ov[c] = keep ? vv[c] : 0.f;
            if (keep) {
                int s = atomicAdd(&sel_cnt, 1);
                if (s < TOPK) { sel_v[s] = vv[c]; sel_j[s] = i; }
            }
        }
        *(float4*)(rowp + i4 * 4) = make_float4(ov[0], ov[1], ov[2], ov[3]);
    }
    __syncthreads();

    // sparse decode: out[row, :] = sum_s v_s * W_dec[j_s, :]
    float a0 = 0.f, a1 = 0.f;
    #pragma unroll 8
    for (int s = 0; s < TOPK; ++s) {
        const float v = sel_v[s];
        const float* wd = Wd + (size_t)sel_j[s] * DMODEL;
        a0 += v * wd[tid];
        if (tid < 256) a1 += v * wd[512 + tid];
    }
    out[(size_t)row * DMODEL + tid] = a0;
    if (tid < 256) out[(size_t)row * DMODEL + 512 + tid] = a1;
}

// =================== launch ===================
extern "C" void kernel_launch(void* const* d_in, const int* in_sizes, int n_in,
                              void* d_out, int out_size, void* d_ws, size_t ws_size,
                              hipStream_t stream) {
    const float* x     = (const float*)d_in[0];
    const float* W_enc = (const float*)d_in[1];
    const float* b_enc = (const float*)d_in[2];
    const float* W_dec = (const float*)d_in[3];
    float* out = (float*)d_out;
    float* lat = out + (size_t)NROWS * DMODEL;   // latents region of d_out

    dim3 g1(DSAE / BN, NROWS / BM);   // (192, 64)
    gemm_enc<<<g1, 256, 0, stream>>>(x, W_enc, b_enc, lat);
    topk_decode<<<NROWS, NT2, 0, stream>>>(lat, W_dec, out);
}